// Round 7
// baseline (183.334 us; speedup 1.0000x reference)
//
#include <hip/hip_runtime.h>
#include <math.h>
#include <stdint.h>

#define B_ 8
#define H_ 56
#define W_ 56
#define C_ 64
#define N_ (H_*W_)        // 3136
#define KT 32
#define NCH (N_/KT)       // 98
#define QTILE 128
#define NTILES 25         // ceil(3136/128)
#define KSPLIT 8
#define SCALE_LOG2 11.5415603271f   // 8 * log2(e)

typedef float    f32x16 __attribute__((ext_vector_type(16)));
typedef short    short8 __attribute__((ext_vector_type(8)));
typedef unsigned u32x4  __attribute__((ext_vector_type(4)));

#define GLOBAL_AS __attribute__((address_space(1)))
#define LDS_AS    __attribute__((address_space(3)))

static __device__ __forceinline__ float bf16lo_f(unsigned w) { return __uint_as_float(w << 16); }
static __device__ __forceinline__ float bf16hi_f(unsigned w) { return __uint_as_float(w & 0xFFFF0000u); }
static __device__ __forceinline__ unsigned pack_bf2(float a, float b) {
    unsigned r;
    asm("v_cvt_pk_bf16_f32 %0, %1, %2" : "=v"(r) : "v"(a), "v"(b));
    return r;
}
static __device__ __forceinline__ float exp2_fast(float x) {
    float r;
    asm("v_exp_f32 %0, %1" : "=v"(r) : "v"(x));
    return r;
}
static __device__ __forceinline__ short8 frag_words(unsigned w0, unsigned w1, unsigned w2, unsigned w3) {
    union { u32x4 u; short8 s; } t;
    t.u = (u32x4){w0, w1, w2, w3};
    return t.s;
}
static __device__ __forceinline__ f32x16 MF(short8 a, short8 b, f32x16 c) {
    return __builtin_amdgcn_mfma_f32_32x32x16_bf16(a, b, c, 0, 0, 0);
}
// K LDS fragment: 256B rows, 16B chunks XOR-swizzled by (row&15)
static __device__ __forceinline__ short8 ldsfragK(const uint8_t* base, int row, int q16) {
    const uint4 u = *(const uint4*)(base + row * 256 + ((q16 ^ (row & 15)) * 16));
    union { uint4 a; short8 s; } t; t.a = u; return t.s;
}
// V LDS fragment: 80B-padded rows (bank spread), plain word index
static __device__ __forceinline__ short8 ldsfragV(const uint8_t* base, int row, int wd) {
    const uint4 u = *(const uint4*)(base + row * 80 + wd * 16);
    union { uint4 a; short8 s; } t; t.a = u; return t.s;
}

// ---------------------------------------------------------------------------
// Kernel 1 (fused): dwconv -> q,k (token-major hi/lo rows; k pre-swizzled for
// LDS) + v (transposed hi). Block = 256 threads = 32 tokens x 64 ch.
// ---------------------------------------------------------------------------
__global__ __launch_bounds__(256)
void dwconv_fused(const float* __restrict__ x,
                  const float* __restrict__ wq, const float* __restrict__ bq,
                  const float* __restrict__ wk, const float* __restrict__ bk,
                  const float* __restrict__ wv, const float* __restrict__ bv,
                  uint8_t* __restrict__ qbuf, uint8_t* __restrict__ kbuf,
                  uint8_t* __restrict__ vtbuf) {
    __shared__ float tq[32][68];
    __shared__ float tk[32][68];

    const int t   = threadIdx.x;
    const int c   = t & 63;
    const int oct = t >> 6;
    const int og  = blockIdx.x * 4 + oct;     // global octet
    const int b   = og / (N_ / 8);
    const int po  = og % (N_ / 8);
    const int h0  = po / 7;
    const int w0  = (po - h0 * 7) * 8;

    float q8[8], k8[8], v8[8];
    const float bqc = bq[c], bkc = bk[c], bvc = bv[c];
    #pragma unroll
    for (int i = 0; i < 8; ++i) { q8[i] = bqc; k8[i] = bkc; v8[i] = bvc; }

    #pragma unroll
    for (int dh = 0; dh < 3; ++dh) {
        int hh = h0 + dh - 1;
        if (hh < 0 || hh >= H_) continue;
        float xv[10];
        #pragma unroll
        for (int j = 0; j < 10; ++j) {
            int ww = w0 + j - 1;
            xv[j] = (ww >= 0 && ww < W_) ? x[(((size_t)b * H_ + hh) * W_ + ww) * C_ + c] : 0.f;
        }
        #pragma unroll
        for (int dw = 0; dw < 3; ++dw) {
            float fq = wq[(dh * 3 + dw) * C_ + c];
            float fk = wk[(dh * 3 + dw) * C_ + c];
            float fv = wv[(dh * 3 + dw) * C_ + c];
            #pragma unroll
            for (int i = 0; i < 8; ++i) {
                float xs = xv[i + dw];
                q8[i] = fmaf(xs, fq, q8[i]);
                k8[i] = fmaf(xs, fk, k8[i]);
                v8[i] = fmaf(xs, fv, v8[i]);
            }
        }
    }
    #pragma unroll
    for (int i = 0; i < 8; ++i) q8[i] *= SCALE_LOG2;

    // ---- v: pack hi, store transposed: vt row = 64B (4 words = 4 octets)
    {
        uint4 vh4; unsigned* vh = (unsigned*)&vh4;
        #pragma unroll
        for (int j = 0; j < 4; ++j) vh[j] = pack_bf2(v8[2*j], v8[2*j+1]);
        int ch32 = po >> 2, ko = po & 3;
        *(uint4*)&vtbuf[((size_t)(b * NCH + ch32) * 64 + c) * 64 + ko * 16] = vh4;
    }

    // ---- q,k: LDS transpose to token-major, pack hi/lo, store ----
    #pragma unroll
    for (int i = 0; i < 8; ++i) { tq[oct * 8 + i][c] = q8[i]; tk[oct * 8 + i][c] = k8[i]; }
    __syncthreads();

    const int g2 = t & 7;       // channel group (8 ch)
    const int tl = t >> 3;      // token-local 0..31
    float qv[8], kv[8];
    *(float4*)&qv[0] = *(const float4*)&tq[tl][8 * g2];
    *(float4*)&qv[4] = *(const float4*)&tq[tl][8 * g2 + 4];
    *(float4*)&kv[0] = *(const float4*)&tk[tl][8 * g2];
    *(float4*)&kv[4] = *(const float4*)&tk[tl][8 * g2 + 4];

    uint4 qh4, ql4, kh4, kl4;
    unsigned* qh = (unsigned*)&qh4; unsigned* ql = (unsigned*)&ql4;
    unsigned* kh = (unsigned*)&kh4; unsigned* kl = (unsigned*)&kl4;
    #pragma unroll
    for (int j = 0; j < 4; ++j) {
        float a0 = qv[2*j], a1 = qv[2*j+1];
        qh[j] = pack_bf2(a0, a1);
        ql[j] = pack_bf2(a0 - bf16lo_f(qh[j] & 0xFFFFu), a1 - bf16hi_f(qh[j]));
        float k0 = kv[2*j], k1 = kv[2*j+1];
        kh[j] = pack_bf2(k0, k1);
        kl[j] = pack_bf2(k0 - bf16lo_f(kh[j] & 0xFFFFu), k1 - bf16hi_f(kh[j]));
    }
    const int nf = blockIdx.x * 32 + tl;      // flat token (b*N_+n); batch mult of 32
    size_t rb = (size_t)nf * 256;
    *(uint4*)&qbuf[rb + g2 * 16]                    = qh4;
    *(uint4*)&qbuf[rb + (8 + g2) * 16]              = ql4;
    *(uint4*)&kbuf[rb + ((g2 ^ (nf & 15))) * 16]       = kh4;
    *(uint4*)&kbuf[rb + (((8 + g2) ^ (nf & 15))) * 16] = kl4;
}

// ---------------------------------------------------------------------------
// Kernel 2: MFMA flash attention, K-split partials, LDS-staged.
// R7 change (T4): raw s_barrier pairs + COUNTED s_waitcnt vmcnt(N) -- the
// ch+1 prefetch stays in flight across the barrier instead of being drained
// by __syncthreads()'s implicit vmcnt(0).
// grid = 1600: bx = ((ks*25+tile)<<3)|b. 4 waves x 32 q-rows. KT=32 chunks.
// LDS: K 2x8KB (swizzled) + V 2x5KB (80B-pad rows) = 26KB.
// ---------------------------------------------------------------------------
__global__ __launch_bounds__(256, 3)
void attn_part(const uint8_t* __restrict__ qbuf, const uint8_t* __restrict__ kbuf,
               const uint8_t* __restrict__ vtbuf,
               float* __restrict__ part, float* __restrict__ ml) {
    __shared__ __align__(16) uint8_t smem[16384 + 10240];

    const int t    = threadIdx.x;
    const int lane = t & 63;
    const int wv_  = t >> 6;         // wave id
    const int h    = lane >> 5;
    const int l31  = lane & 31;
    const int bx   = blockIdx.x;
    const int b    = bx & 7;
    const int r2   = bx >> 3;        // 0..199
    const int ks   = r2 / NTILES;
    const int tile = r2 % NTILES;
    const int q0   = tile * QTILE;

    const int c_beg = (NCH * ks) / KSPLIT;
    const int c_end = (NCH * (ks + 1)) / KSPLIT;

    // ---- Q fragments: channels c = 16s + 8h + j ----
    const int qu = q0 + wv_ * 32 + l31;
    const int qr = qu < N_ ? qu : N_ - 1;
    const uint8_t* qrp = qbuf + ((size_t)(b * N_ + qr)) * 256;
    short8 qh[4], ql[4];
    #pragma unroll
    for (int s = 0; s < 4; ++s) {
        union { uint4 a; short8 s8; } th, tl_;
        th.a  = *(const uint4*)(qrp + s * 32 + h * 16);
        tl_.a = *(const uint4*)(qrp + 128 + s * 32 + h * 16);
        qh[s] = th.s8; ql[s] = tl_.s8;
    }

    f32x16 ctx0, ctx1;
    #pragma unroll
    for (int i = 0; i < 16; ++i) { ctx0[i] = 0.f; ctx1[i] = 0.f; }
    float mrun = -INFINITY, lrun = 0.f;

    // V stage slot mapping (fixed per thread): slot -> (c = slot/5, j = slot%5)
    const int slA = t, slB = 256 + t;
    const int vsA = (slA / 5) * 64 + ((slA % 5) == 4 ? 0 : (slA % 5)) * 16;
    const int vsB = (slB / 5) * 64 + ((slB % 5) == 4 ? 0 : (slB % 5)) * 16;

    // per-chunk loads issued by this thread: wave 0 -> 4, waves 1-3 -> 3
    auto stage = [&](int ch, int pb) {
        const uint8_t* ksrc = kbuf  + ((size_t)(b * N_ + ch * KT)) * 256;
        const uint8_t* vsrc = vtbuf + ((size_t)(b * NCH + ch)) * 4096;
        uint8_t* kd = smem + pb * 8192;
        uint8_t* vd = smem + 16384 + pb * 5120;
        __builtin_amdgcn_global_load_lds((const GLOBAL_AS uint32_t*)(ksrc + t * 16),
                                         (LDS_AS uint32_t*)(kd + t * 16), 16, 0, 0);
        __builtin_amdgcn_global_load_lds((const GLOBAL_AS uint32_t*)(ksrc + t * 16 + 4096),
                                         (LDS_AS uint32_t*)(kd + t * 16 + 4096), 16, 0, 0);
        __builtin_amdgcn_global_load_lds((const GLOBAL_AS uint32_t*)(vsrc + vsA),
                                         (LDS_AS uint32_t*)(vd + slA * 16), 16, 0, 0);
        if (t < 64)
            __builtin_amdgcn_global_load_lds((const GLOBAL_AS uint32_t*)(vsrc + vsB),
                                             (LDS_AS uint32_t*)(vd + slB * 16), 16, 0, 0);
    };

    stage(c_beg, 0);
    asm volatile("s_waitcnt vmcnt(0)" ::: "memory");
    __builtin_amdgcn_sched_barrier(0);
    __builtin_amdgcn_s_barrier();

    for (int ch = c_beg; ch < c_end; ++ch) {
        const int pb = (ch - c_beg) & 1;
        const uint8_t* Kp = smem + pb * 8192;
        const uint8_t* Vp = smem + 16384 + pb * 5120;

        // issue ch+1 prefetch, then wait ONLY for ch's loads (counted vmcnt)
        if (ch + 1 < c_end) {
            stage(ch + 1, pb ^ 1);
            if (wv_ == 0) { asm volatile("s_waitcnt vmcnt(4)" ::: "memory"); }
            else          { asm volatile("s_waitcnt vmcnt(3)" ::: "memory"); }
        } else {
            asm volatile("s_waitcnt vmcnt(0)" ::: "memory");
        }
        __builtin_amdgcn_sched_barrier(0);
        __builtin_amdgcn_s_barrier();     // A: chunk ch resident for all waves
        __builtin_amdgcn_sched_barrier(0);

        // ---- S^T = K * Q^T (hi/lo 3-term), one 32-row k-tile ----
        f32x16 s0;
        #pragma unroll
        for (int i = 0; i < 16; ++i) s0[i] = 0.f;
        #pragma unroll
        for (int s = 0; s < 4; ++s) {
            short8 kh0 = ldsfragK(Kp, l31, 2 * s + h);
            short8 kl0 = ldsfragK(Kp, l31, 8 + 2 * s + h);
            s0 = MF(kh0, qh[s], s0);
            s0 = MF(kh0, ql[s], s0);
            s0 = MF(kl0, qh[s], s0);
        }

        // ---- online softmax (log2 domain) ----
        float mloc = s0[0];
        #pragma unroll
        for (int i = 1; i < 16; ++i) mloc = fmaxf(mloc, s0[i]);
        float mw = fmaxf(mloc, __shfl_xor(mloc, 32));
        if (mw > mrun + 8.f) {          // defer-max (T13)
            float fac = exp2_fast(mrun - mw);
            lrun *= fac;
            #pragma unroll
            for (int i = 0; i < 16; ++i) { ctx0[i] *= fac; ctx1[i] *= fac; }
            mrun = mw;
        }
        float p0[16];
        float lsum = 0.f;
        #pragma unroll
        for (int i = 0; i < 16; ++i) { p0[i] = exp2_fast(s0[i] - mrun); lsum += p0[i]; }
        lrun += lsum + __shfl_xor(lsum, 32);

        // ---- P -> bf16 hi/lo words ----
        unsigned hw0[8], lw0[8];
        #pragma unroll
        for (int j = 0; j < 8; ++j) {
            hw0[j] = pack_bf2(p0[2*j], p0[2*j+1]);
            lw0[j] = pack_bf2(p0[2*j]   - bf16lo_f(hw0[j] & 0xFFFFu),
                              p0[2*j+1] - bf16hi_f(hw0[j]));
        }

        // ---- PV ----
#define PV_STEP(S) {                                                          \
        const int base = 4 * (S);                                             \
        unsigned a0 = hw0[base], a1 = hw0[base+1], a2 = hw0[base+2], a3 = hw0[base+3]; \
        unsigned c0 = lw0[base], c1 = lw0[base+1], c2 = lw0[base+2], c3 = lw0[base+3]; \
        unsigned sh0 = __shfl_xor(h ? a0 : a2, 32);                           \
        unsigned sh1 = __shfl_xor(h ? a1 : a3, 32);                           \
        unsigned sl0 = __shfl_xor(h ? c0 : c2, 32);                           \
        unsigned sl1 = __shfl_xor(h ? c1 : c3, 32);                           \
        short8 bh = frag_words(h ? sh0 : a0, h ? sh1 : a1,                    \
                               h ? a2 : sh0, h ? a3 : sh1);                   \
        short8 bl = frag_words(h ? sl0 : c0, h ? sl1 : c1,                    \
                               h ? c2 : sl0, h ? c3 : sl1);                   \
        short8 v0f = ldsfragV(Vp, l31,      2 * (S) + h);                     \
        short8 v1f = ldsfragV(Vp, 32 + l31, 2 * (S) + h);                     \
        ctx0 = MF(v0f, bh, ctx0);  ctx1 = MF(v1f, bh, ctx1);                  \
        ctx0 = MF(v0f, bl, ctx0);  ctx1 = MF(v1f, bl, ctx1);                  \
    }
        PV_STEP(0)
        PV_STEP(1)
#undef PV_STEP

        __builtin_amdgcn_sched_barrier(0);
        __builtin_amdgcn_s_barrier();     // B: all waves done reading chunk ch
        __builtin_amdgcn_sched_barrier(0);
    }

    // ---- write partials: part[bx][c:64][q:128], ml[bx][q][2] ----
    float* pbase = part + (size_t)bx * 8192 + (wv_ * 32 + l31);
    #pragma unroll
    for (int u = 0; u < 4; ++u)
        #pragma unroll
        for (int rr = 0; rr < 4; ++rr) {
            int cc = 8 * u + 4 * h + rr;
            pbase[(size_t)cc * 128]        = ctx0[4*u + rr];
            pbase[(size_t)(cc + 32) * 128] = ctx1[4*u + rr];
        }
    if (h == 0)
        ((float2*)ml)[(size_t)bx * 128 + wv_ * 32 + l31] = make_float2(mrun, lrun);
}

// ---------------------------------------------------------------------------
// Kernel 3: combine 8 K-split partials + projection. grid = 400:
// bx = ((tile*2+half)<<3)|b, each block does 64 q-rows.
// ---------------------------------------------------------------------------
__global__ __launch_bounds__(256)
void combine(const float* __restrict__ part, const float* __restrict__ ml,
             const float* __restrict__ Wp, const float* __restrict__ bp,
             float* __restrict__ out) {
    __shared__ float cm[64][68];        // merged+normalized ctx, c-major
    __shared__ float fac[KSPLIT][64];

    const int bx   = blockIdx.x;
    const int b    = bx & 7;
    const int r2   = bx >> 3;
    const int tile = r2 >> 1;
    const int half = r2 & 1;
    const int qoff = half * 64;
    const int t    = threadIdx.x;

    if (t < 64) {
        float m8[KSPLIT], l8[KSPLIT];
        #pragma unroll
        for (int ks = 0; ks < KSPLIT; ++ks) {
            float2 v = ((const float2*)ml)[((size_t)((ks * NTILES + tile) * 8 + b)) * 128 + qoff + t];
            m8[ks] = v.x; l8[ks] = v.y;
        }
        float M = m8[0];
        #pragma unroll
        for (int ks = 1; ks < KSPLIT; ++ks) M = fmaxf(M, m8[ks]);
        float L = 0.f;
        float f[KSPLIT];
        #pragma unroll
        for (int ks = 0; ks < KSPLIT; ++ks) { f[ks] = exp2f(m8[ks] - M); L = fmaf(l8[ks], f[ks], L); }
        float inv = 1.f / L;
        #pragma unroll
        for (int ks = 0; ks < KSPLIT; ++ks) fac[ks][t] = f[ks] * inv;
    }
    __syncthreads();

    // ---- merge, fully coalesced: idx -> (c = idx>>4, q4 = idx&15) ----
    #pragma unroll
    for (int rep = 0; rep < 4; ++rep) {
        const int idx = rep * 256 + t;        // 0..1023
        const int c   = idx >> 4;
        const int q4  = idx & 15;
        float4 acc = make_float4(0.f, 0.f, 0.f, 0.f);
        #pragma unroll
        for (int ks = 0; ks < KSPLIT; ++ks) {
            const float4 p4 = *(const float4*)&part[((size_t)((ks * NTILES + tile) * 8 + b)) * 8192
                                                    + c * 128 + qoff + q4 * 4];
            const float4 f4 = *(const float4*)&fac[ks][q4 * 4];
            acc.x = fmaf(p4.x, f4.x, acc.x);
            acc.y = fmaf(p4.y, f4.y, acc.y);
            acc.z = fmaf(p4.z, f4.z, acc.z);
            acc.w = fmaf(p4.w, f4.w, acc.w);
        }
        *(float4*)&cm[c][q4 * 4] = acc;
    }
    __syncthreads();

    // ---- projection: thread -> (q = t>>2, eq = t&3): 16 e-cols each ----
    {
        const int q = t >> 2, eq = t & 3;
        float4 y[4];
        #pragma unroll
        for (int e = 0; e < 4; ++e) y[e] = *(const float4*)&bp[eq * 16 + e * 4];
        for (int cc = 0; cc < 64; ++cc) {
            float v = cm[cc][q];
            const float4* w4 = (const float4*)&Wp[cc * 64 + eq * 16];
            #pragma unroll
            for (int e = 0; e < 4; ++e) {
                float4 wv4 = w4[e];
                y[e].x = fmaf(v, wv4.x, y[e].x);
                y[e].y = fmaf(v, wv4.y, y[e].y);
                y[e].z = fmaf(v, wv4.z, y[e].z);
                y[e].w = fmaf(v, wv4.w, y[e].w);
            }
        }
        const int n = tile * QTILE + qoff + q;
        if (n < N_) {
            float4* op = (float4*)&out[((size_t)b * N_ + n) * 64 + eq * 16];
            #pragma unroll
            for (int e = 0; e < 4; ++e) op[e] = y[e];
        }
    }
}

// ---------------------------------------------------------------------------
extern "C" void kernel_launch(void* const* d_in, const int* in_sizes, int n_in,
                              void* d_out, int out_size, void* d_ws, size_t ws_size,
                              hipStream_t stream) {
    const float* x  = (const float*)d_in[0];
    const float* wq = (const float*)d_in[1];
    const float* bq = (const float*)d_in[2];
    const float* wk = (const float*)d_in[3];
    const float* bk = (const float*)d_in[4];
    const float* wv = (const float*)d_in[5];
    const float* bv = (const float*)d_in[6];
    const float* Wp = (const float*)d_in[7];
    const float* bp = (const float*)d_in[8];
    float* out = (float*)d_out;

    const size_t qk_bytes = (size_t)B_ * N_ * 256;          // 6,422,528 each
    const size_t vt_bytes = (size_t)B_ * NCH * 64 * 64;     // 3,211,264
    uint8_t* qbuf  = (uint8_t*)d_ws;
    uint8_t* kbuf  = qbuf + qk_bytes;
    uint8_t* vtbuf = kbuf + qk_bytes;
    float*   partp = (float*)(vtbuf + vt_bytes);            // [1600][64][128] f32
    float*   mlp   = partp + (size_t)1600 * 64 * 128;       // [1600][128][2]

    dwconv_fused<<<784, 256, 0, stream>>>(x, wq, bq, wk, bk, wv, bv, qbuf, kbuf, vtbuf);
    attn_part<<<8 * NTILES * KSPLIT, 256, 0, stream>>>(qbuf, kbuf, vtbuf, partp, mlp);
    combine<<<8 * NTILES * 2, 256, 0, stream>>>(partp, mlp, Wp, bp, out);
}

// Round 9
// 182.888 us; speedup vs baseline: 1.0024x; 1.0024x over previous
//
#include <hip/hip_runtime.h>
#include <math.h>
#include <stdint.h>

#define B_ 8
#define H_ 56
#define W_ 56
#define C_ 64
#define N_ (H_*W_)        // 3136
#define KT 32
#define NCH (N_/KT)       // 98
#define KSPLIT 8
#define SCALE_LOG2 11.5415603271f   // 8 * log2(e)

typedef float    f32x16 __attribute__((ext_vector_type(16)));
typedef short    short8 __attribute__((ext_vector_type(8)));
typedef unsigned u32x4  __attribute__((ext_vector_type(4)));

static __device__ __forceinline__ float bf16lo_f(unsigned w) { return __uint_as_float(w << 16); }
static __device__ __forceinline__ float bf16hi_f(unsigned w) { return __uint_as_float(w & 0xFFFF0000u); }
static __device__ __forceinline__ unsigned pack_bf2(float a, float b) {
    unsigned r;
    asm("v_cvt_pk_bf16_f32 %0, %1, %2" : "=v"(r) : "v"(a), "v"(b));
    return r;
}
static __device__ __forceinline__ float exp2_fast(float x) {
    float r;
    asm("v_exp_f32 %0, %1" : "=v"(r) : "v"(x));
    return r;
}
static __device__ __forceinline__ short8 frag_words(unsigned w0, unsigned w1, unsigned w2, unsigned w3) {
    union { u32x4 u; short8 s; } t;
    t.u = (u32x4){w0, w1, w2, w3};
    return t.s;
}
static __device__ __forceinline__ f32x16 MF(short8 a, short8 b, f32x16 c) {
    return __builtin_amdgcn_mfma_f32_32x32x16_bf16(a, b, c, 0, 0, 0);
}
// 16B global fragment load (fragment-major layout -> fully coalesced per wave)
static __device__ __forceinline__ short8 ldf(const uint8_t* p) {
    union { uint4 a; short8 s; } t;
    t.a = *(const uint4*)p;
    return t.s;
}

// ---------------------------------------------------------------------------
// Kernel 1 (fused): dwconv -> q,k,v stored FRAGMENT-MAJOR:
//  q/k per 32-token tile: [b*98+t32][hl:2][g:8][tok:32][16B]  (8 KB/tile)
//      g = channel group (16B = ch 16s+8h..+7, g = 2s+h), tok = n&31
//  v  per 32-token chunk: [b*98+ch][g:4][c:64][16B]           (4 KB/chunk)
//      g = token word (tokens 8g..8g+7), c = channel row, hi only
// Block = 256 threads = 32 consecutive tokens (one tile) x 64 ch.
// ---------------------------------------------------------------------------
__global__ __launch_bounds__(256)
void dwconv_fused(const float* __restrict__ x,
                  const float* __restrict__ wq, const float* __restrict__ bq,
                  const float* __restrict__ wk, const float* __restrict__ bk,
                  const float* __restrict__ wv, const float* __restrict__ bv,
                  uint8_t* __restrict__ qf, uint8_t* __restrict__ kf,
                  uint8_t* __restrict__ vf) {
    __shared__ float tq[32][68];
    __shared__ float tk[32][68];

    const int t   = threadIdx.x;
    const int c   = t & 63;
    const int oct = t >> 6;
    const int og  = blockIdx.x * 4 + oct;     // global octet (8 tokens)
    const int b   = og / (N_ / 8);
    const int po  = og % (N_ / 8);
    const int h0  = po / 7;
    const int w0  = (po - h0 * 7) * 8;

    float q8[8], k8[8], v8[8];
    const float bqc = bq[c], bkc = bk[c], bvc = bv[c];
    #pragma unroll
    for (int i = 0; i < 8; ++i) { q8[i] = bqc; k8[i] = bkc; v8[i] = bvc; }

    #pragma unroll
    for (int dh = 0; dh < 3; ++dh) {
        int hh = h0 + dh - 1;
        if (hh < 0 || hh >= H_) continue;
        float xv[10];
        #pragma unroll
        for (int j = 0; j < 10; ++j) {
            int ww = w0 + j - 1;
            xv[j] = (ww >= 0 && ww < W_) ? x[(((size_t)b * H_ + hh) * W_ + ww) * C_ + c] : 0.f;
        }
        #pragma unroll
        for (int dw = 0; dw < 3; ++dw) {
            float fq = wq[(dh * 3 + dw) * C_ + c];
            float fk = wk[(dh * 3 + dw) * C_ + c];
            float fv = wv[(dh * 3 + dw) * C_ + c];
            #pragma unroll
            for (int i = 0; i < 8; ++i) {
                float xs = xv[i + dw];
                q8[i] = fmaf(xs, fq, q8[i]);
                k8[i] = fmaf(xs, fk, k8[i]);
                v8[i] = fmaf(xs, fv, v8[i]);
            }
        }
    }
    #pragma unroll
    for (int i = 0; i < 8; ++i) q8[i] *= SCALE_LOG2;

    // ---- v: pack hi, fragment-major: [og>>2][g=og&3][c] ----
    {
        uint4 vh4; unsigned* vh = (unsigned*)&vh4;
        #pragma unroll
        for (int j = 0; j < 4; ++j) vh[j] = pack_bf2(v8[2*j], v8[2*j+1]);
        *(uint4*)&vf[((size_t)(og >> 2)) * 4096 + (og & 3) * 1024 + c * 16] = vh4;
    }

    // ---- q,k: LDS transpose to token-major, pack hi/lo, store frag-major ----
    #pragma unroll
    for (int i = 0; i < 8; ++i) { tq[oct * 8 + i][c] = q8[i]; tk[oct * 8 + i][c] = k8[i]; }
    __syncthreads();

    const int g2 = t & 7;       // channel group (8 ch = one 16B fragment)
    const int tl = t >> 3;      // token-local 0..31
    float qv[8], kv[8];
    *(float4*)&qv[0] = *(const float4*)&tq[tl][8 * g2];
    *(float4*)&qv[4] = *(const float4*)&tq[tl][8 * g2 + 4];
    *(float4*)&kv[0] = *(const float4*)&tk[tl][8 * g2];
    *(float4*)&kv[4] = *(const float4*)&tk[tl][8 * g2 + 4];

    uint4 qh4, ql4, kh4, kl4;
    unsigned* qh = (unsigned*)&qh4; unsigned* ql = (unsigned*)&ql4;
    unsigned* kh = (unsigned*)&kh4; unsigned* kl = (unsigned*)&kl4;
    #pragma unroll
    for (int j = 0; j < 4; ++j) {
        float a0 = qv[2*j], a1 = qv[2*j+1];
        qh[j] = pack_bf2(a0, a1);
        ql[j] = pack_bf2(a0 - bf16lo_f(qh[j] & 0xFFFFu), a1 - bf16hi_f(qh[j]));
        float k0 = kv[2*j], k1 = kv[2*j+1];
        kh[j] = pack_bf2(k0, k1);
        kl[j] = pack_bf2(k0 - bf16lo_f(kh[j] & 0xFFFFu), k1 - bf16hi_f(kh[j]));
    }
    const int nf = blockIdx.x * 32 + tl;      // flat token (b*N_+n)
    const size_t tb = ((size_t)(nf >> 5)) * 8192;   // (b*98 + tile32) * 8KB
    *(uint4*)&qf[tb +        g2 * 512 + tl * 16] = qh4;
    *(uint4*)&qf[tb + 4096 + g2 * 512 + tl * 16] = ql4;
    *(uint4*)&kf[tb +        g2 * 512 + tl * 16] = kh4;
    *(uint4*)&kf[tb + 4096 + g2 * 512 + tl * 16] = kl4;
}

// ---------------------------------------------------------------------------
// Kernel 2: MFMA flash attention — NO LDS, NO barriers, 1-wave blocks.
// grid = 6272: bx = ((ks*98 + qt32)<<3)|b  (b -> XCD L2 affinity).
// Each wave owns 32 q-rows, iterates its K-split chunk segment; all K/V/Q
// fragment loads are lane-linear 16B (coalesced 1KB/instr), L2-resident.
// Numerics identical to R6 (hi/lo P, 3-term QK, shfl_xor exchanges).
// ---------------------------------------------------------------------------
__global__ __launch_bounds__(64, 4)
void attn_part(const uint8_t* __restrict__ qf, const uint8_t* __restrict__ kf,
               const uint8_t* __restrict__ vf,
               float* __restrict__ part, float* __restrict__ ml) {
    const int lane = threadIdx.x;
    const int h    = lane >> 5;
    const int l31  = lane & 31;
    const int bx   = blockIdx.x;
    const int b    = bx & 7;
    const int r    = bx >> 3;        // 0..783
    const int ks   = r / NCH;
    const int qt   = r % NCH;

    const int c_beg = (NCH * ks) / KSPLIT;
    const int c_end = (NCH * (ks + 1)) / KSPLIT;

    // ---- Q fragments (B-operand), lane-linear ----
    const uint8_t* qb = qf + ((size_t)(b * NCH + qt)) * 8192;
    short8 qh[4], ql[4];
    #pragma unroll
    for (int s = 0; s < 4; ++s) {
        qh[s] = ldf(qb + s * 1024 + lane * 16);
        ql[s] = ldf(qb + 4096 + s * 1024 + lane * 16);
    }

    f32x16 ctx0, ctx1;
    #pragma unroll
    for (int i = 0; i < 16; ++i) { ctx0[i] = 0.f; ctx1[i] = 0.f; }
    float mrun = -INFINITY, lrun = 0.f;

    for (int ch = c_beg; ch < c_end; ++ch) {
        const uint8_t* kb = kf + ((size_t)(b * NCH + ch)) * 8192;
        const uint8_t* vb = vf + ((size_t)(b * NCH + ch)) * 4096;
        // K fragments: lane-linear (A-operand: own token row l31, k-chunk 2s+h)
        short8 kh0 = ldf(kb +        lane * 16);
        short8 kh1 = ldf(kb + 1024 + lane * 16);
        short8 kh2 = ldf(kb + 2048 + lane * 16);
        short8 kh3 = ldf(kb + 3072 + lane * 16);
        short8 kl0 = ldf(kb + 4096 + lane * 16);
        short8 kl1 = ldf(kb + 5120 + lane * 16);
        short8 kl2 = ldf(kb + 6144 + lane * 16);
        short8 kl3 = ldf(kb + 7168 + lane * 16);
        // V fragments (A-operand: channel row, token-word 2S+h)
        short8 v00 = ldf(vb +        h * 1024 + l31 * 16);        // S=0, c 0-31
        short8 v10 = ldf(vb +  512 + h * 1024 + l31 * 16);        // S=0, c 32-63
        short8 v01 = ldf(vb + 2048 + h * 1024 + l31 * 16);        // S=1, c 0-31
        short8 v11 = ldf(vb + 2560 + h * 1024 + l31 * 16);        // S=1, c 32-63

        // ---- S^T = K * Q^T (hi/lo 3-term), 32k x 32q ----
        f32x16 s0;
        #pragma unroll
        for (int i = 0; i < 16; ++i) s0[i] = 0.f;
        s0 = MF(kh0, qh[0], s0); s0 = MF(kh0, ql[0], s0); s0 = MF(kl0, qh[0], s0);
        s0 = MF(kh1, qh[1], s0); s0 = MF(kh1, ql[1], s0); s0 = MF(kl1, qh[1], s0);
        s0 = MF(kh2, qh[2], s0); s0 = MF(kh2, ql[2], s0); s0 = MF(kl2, qh[2], s0);
        s0 = MF(kh3, qh[3], s0); s0 = MF(kh3, ql[3], s0); s0 = MF(kl3, qh[3], s0);

        // ---- online softmax (log2 domain), exact max tree + shfl ----
        float t0 = fmaxf(fmaxf(s0[0],  s0[1]),  s0[2]);
        float t1 = fmaxf(fmaxf(s0[3],  s0[4]),  s0[5]);
        float t2 = fmaxf(fmaxf(s0[6],  s0[7]),  s0[8]);
        float t3 = fmaxf(fmaxf(s0[9],  s0[10]), s0[11]);
        float t4 = fmaxf(fmaxf(s0[12], s0[13]), s0[14]);
        float mloc = fmaxf(fmaxf(fmaxf(t0, t1), s0[15]), fmaxf(fmaxf(t2, t3), t4));
        float mw = fmaxf(mloc, __shfl_xor(mloc, 32));
        if (mw > mrun + 8.f) {          // defer-max (T13)
            float fac = exp2_fast(mrun - mw);
            lrun *= fac;
            #pragma unroll
            for (int i = 0; i < 16; ++i) { ctx0[i] *= fac; ctx1[i] *= fac; }
            mrun = mw;
        }
        float p0[16];
        float lsum = 0.f;
        #pragma unroll
        for (int i = 0; i < 16; ++i) { p0[i] = exp2_fast(s0[i] - mrun); lsum += p0[i]; }
        lrun += lsum + __shfl_xor(lsum, 32);

        // ---- P -> bf16 hi/lo words ----
        unsigned hw0[8], lw0[8];
        #pragma unroll
        for (int j = 0; j < 8; ++j) {
            hw0[j] = pack_bf2(p0[2*j], p0[2*j+1]);
            lw0[j] = pack_bf2(p0[2*j]   - bf16lo_f(hw0[j] & 0xFFFFu),
                              p0[2*j+1] - bf16hi_f(hw0[j]));
        }

        // ---- PV: partner word exchange -> B-frags; A = V from regs ----
#define PV_STEP(S, VA, VB) {                                                  \
        const int base = 4 * (S);                                             \
        unsigned a0 = hw0[base], a1 = hw0[base+1], a2 = hw0[base+2], a3 = hw0[base+3]; \
        unsigned c0 = lw0[base], c1 = lw0[base+1], c2 = lw0[base+2], c3 = lw0[base+3]; \
        unsigned sh0 = __shfl_xor(h ? a0 : a2, 32);                           \
        unsigned sh1 = __shfl_xor(h ? a1 : a3, 32);                           \
        unsigned sl0 = __shfl_xor(h ? c0 : c2, 32);                           \
        unsigned sl1 = __shfl_xor(h ? c1 : c3, 32);                           \
        short8 bh = frag_words(h ? sh0 : a0, h ? sh1 : a1,                    \
                               h ? a2 : sh0, h ? a3 : sh1);                   \
        short8 bl = frag_words(h ? sl0 : c0, h ? sl1 : c1,                    \
                               h ? c2 : sl0, h ? c3 : sl1);                   \
        ctx0 = MF(VA, bh, ctx0);  ctx1 = MF(VB, bh, ctx1);                    \
        ctx0 = MF(VA, bl, ctx0);  ctx1 = MF(VB, bl, ctx1);                    \
    }
        PV_STEP(0, v00, v10)
        PV_STEP(1, v01, v11)
#undef PV_STEP
    }

    // ---- write partials: part[bx][c:64][q:32], ml[bx][q:32] ----
    float* pbase = part + (size_t)bx * 2048 + l31;
    #pragma unroll
    for (int u = 0; u < 4; ++u)
        #pragma unroll
        for (int rr = 0; rr < 4; ++rr) {
            int cc = 8 * u + 4 * h + rr;
            pbase[(size_t)cc * 32]        = ctx0[4*u + rr];
            pbase[(size_t)(cc + 32) * 32] = ctx1[4*u + rr];
        }
    if (h == 0)
        ((float2*)ml)[(size_t)bx * 32 + l31] = make_float2(mrun, lrun);
}

// ---------------------------------------------------------------------------
// Kernel 3: combine 8 K-split partials + projection. grid = 392:
// bx = (g<<3)|b, g = 0..48, each block does 64 q-rows (two 32-row tiles).
// ---------------------------------------------------------------------------
__global__ __launch_bounds__(256)
void combine(const float* __restrict__ part, const float* __restrict__ ml,
             const float* __restrict__ Wp, const float* __restrict__ bp,
             float* __restrict__ out) {
    __shared__ float cm[64][68];        // merged+normalized ctx, c-major
    __shared__ float fac[KSPLIT][64];

    const int bx = blockIdx.x;
    const int b  = bx & 7;
    const int g  = bx >> 3;             // 0..48
    const int t  = threadIdx.x;

    if (t < 64) {
        const int qt   = g * 2 + (t >> 5);
        const int qrow = t & 31;
        float m8[KSPLIT], l8[KSPLIT];
        #pragma unroll
        for (int ks = 0; ks < KSPLIT; ++ks) {
            float2 v = ((const float2*)ml)[((size_t)(((ks * NCH + qt) << 3) | b)) * 32 + qrow];
            m8[ks] = v.x; l8[ks] = v.y;
        }
        float M = m8[0];
        #pragma unroll
        for (int ks = 1; ks < KSPLIT; ++ks) M = fmaxf(M, m8[ks]);
        float L = 0.f;
        float f[KSPLIT];
        #pragma unroll
        for (int ks = 0; ks < KSPLIT; ++ks) { f[ks] = exp2f(m8[ks] - M); L = fmaf(l8[ks], f[ks], L); }
        float inv = 1.f / L;
        #pragma unroll
        for (int ks = 0; ks < KSPLIT; ++ks) fac[ks][t] = f[ks] * inv;
    }
    __syncthreads();

    // ---- merge, coalesced: idx -> (c = idx>>4, q = (idx&15)*4) ----
    #pragma unroll
    for (int rep = 0; rep < 4; ++rep) {
        const int idx = rep * 256 + t;        // 0..1023
        const int c   = idx >> 4;
        const int q   = (idx & 15) * 4;       // 0..60
        const int qt  = g * 2 + (q >> 5);
        const int qr  = q & 31;
        float4 acc = make_float4(0.f, 0.f, 0.f, 0.f);
        #pragma unroll
        for (int ks = 0; ks < KSPLIT; ++ks) {
            const float4 p4 = *(const float4*)&part[((size_t)(((ks * NCH + qt) << 3) | b)) * 2048
                                                    + c * 32 + qr];
            const float4 f4 = *(const float4*)&fac[ks][q];
            acc.x = fmaf(p4.x, f4.x, acc.x);
            acc.y = fmaf(p4.y, f4.y, acc.y);
            acc.z = fmaf(p4.z, f4.z, acc.z);
            acc.w = fmaf(p4.w, f4.w, acc.w);
        }
        *(float4*)&cm[c][q] = acc;
    }
    __syncthreads();

    // ---- projection: thread -> (q = t>>2, eq = t&3): 16 e-cols each ----
    {
        const int q = t >> 2, eq = t & 3;
        float4 y[4];
        #pragma unroll
        for (int e = 0; e < 4; ++e) y[e] = *(const float4*)&bp[eq * 16 + e * 4];
        for (int cc = 0; cc < 64; ++cc) {
            float v = cm[cc][q];
            const float4* w4 = (const float4*)&Wp[cc * 64 + eq * 16];
            #pragma unroll
            for (int e = 0; e < 4; ++e) {
                float4 wv4 = w4[e];
                y[e].x = fmaf(v, wv4.x, y[e].x);
                y[e].y = fmaf(v, wv4.y, y[e].y);
                y[e].z = fmaf(v, wv4.z, y[e].z);
                y[e].w = fmaf(v, wv4.w, y[e].w);
            }
        }
        const int n = g * 64 + q;             // < 3136 always (49*64 = 3136)
        float4* op = (float4*)&out[((size_t)b * N_ + n) * 64 + eq * 16];
        #pragma unroll
        for (int e = 0; e < 4; ++e) op[e] = y[e];
    }
}

// ---------------------------------------------------------------------------
extern "C" void kernel_launch(void* const* d_in, const int* in_sizes, int n_in,
                              void* d_out, int out_size, void* d_ws, size_t ws_size,
                              hipStream_t stream) {
    const float* x  = (const float*)d_in[0];
    const float* wq = (const float*)d_in[1];
    const float* bq = (const float*)d_in[2];
    const float* wk = (const float*)d_in[3];
    const float* bk = (const float*)d_in[4];
    const float* wv = (const float*)d_in[5];
    const float* bv = (const float*)d_in[6];
    const float* Wp = (const float*)d_in[7];
    const float* bp = (const float*)d_in[8];
    float* out = (float*)d_out;

    const size_t qk_bytes = (size_t)B_ * NCH * 8192;   // 6,422,528 each
    const size_t vf_bytes = (size_t)B_ * NCH * 4096;   // 3,211,264
    uint8_t* qf = (uint8_t*)d_ws;
    uint8_t* kf = qf + qk_bytes;
    uint8_t* vf = kf + qk_bytes;
    float*   partp = (float*)(vf + vf_bytes);          // [6272][64][32] f32
    float*   mlp   = partp + (size_t)6272 * 2048;      // [6272][32][2]

    dwconv_fused<<<784, 256, 0, stream>>>(x, wq, bq, wk, bk, wv, bv, qf, kf, vf);
    attn_part<<<KSPLIT * NCH * 8, 64, 0, stream>>>(qf, kf, vf, partp, mlp);
    combine<<<49 * 8, 256, 0, stream>>>(partp, mlp, Wp, bp, out);
}

// Round 10
// 176.287 us; speedup vs baseline: 1.0400x; 1.0374x over previous
//
#include <hip/hip_runtime.h>
#include <math.h>
#include <stdint.h>

#define B_ 8
#define H_ 56
#define W_ 56
#define C_ 64
#define N_ (H_*W_)        // 3136
#define KT 32
#define NCH (N_/KT)       // 98
#define KSPLIT 4
#define SCALE_LOG2 11.5415603271f   // 8 * log2(e)

typedef float    f32x16 __attribute__((ext_vector_type(16)));
typedef short    short8 __attribute__((ext_vector_type(8)));
typedef unsigned u32x4  __attribute__((ext_vector_type(4)));

static __device__ __forceinline__ float bf16lo_f(unsigned w) { return __uint_as_float(w << 16); }
static __device__ __forceinline__ float bf16hi_f(unsigned w) { return __uint_as_float(w & 0xFFFF0000u); }
static __device__ __forceinline__ unsigned pack_bf2(float a, float b) {
    unsigned r;
    asm("v_cvt_pk_bf16_f32 %0, %1, %2" : "=v"(r) : "v"(a), "v"(b));
    return r;
}
static __device__ __forceinline__ float exp2_fast(float x) {
    float r;
    asm("v_exp_f32 %0, %1" : "=v"(r) : "v"(x));
    return r;
}
static __device__ __forceinline__ short8 frag_words(unsigned w0, unsigned w1, unsigned w2, unsigned w3) {
    union { u32x4 u; short8 s; } t;
    t.u = (u32x4){w0, w1, w2, w3};
    return t.s;
}
static __device__ __forceinline__ f32x16 MF(short8 a, short8 b, f32x16 c) {
    return __builtin_amdgcn_mfma_f32_32x32x16_bf16(a, b, c, 0, 0, 0);
}
// 16B global fragment load (fragment-major layout -> fully coalesced per wave)
static __device__ __forceinline__ short8 ldf(const uint8_t* p) {
    union { uint4 a; short8 s; } t;
    t.a = *(const uint4*)p;
    return t.s;
}

// ---------------------------------------------------------------------------
// Kernel 1 (fused): dwconv -> q,k,v stored FRAGMENT-MAJOR:
//  q/k per 32-token tile: [b*98+t32][hl:2][g:8][tok:32][16B]  (8 KB/tile)
//  v  per 32-token chunk: [b*98+ch][g:4][c:64][16B]           (4 KB/chunk)
// Block = 256 threads = 32 consecutive tokens (one tile) x 64 ch.
// ---------------------------------------------------------------------------
__global__ __launch_bounds__(256)
void dwconv_fused(const float* __restrict__ x,
                  const float* __restrict__ wq, const float* __restrict__ bq,
                  const float* __restrict__ wk, const float* __restrict__ bk,
                  const float* __restrict__ wv, const float* __restrict__ bv,
                  uint8_t* __restrict__ qf, uint8_t* __restrict__ kf,
                  uint8_t* __restrict__ vf) {
    __shared__ float tq[32][68];
    __shared__ float tk[32][68];

    const int t   = threadIdx.x;
    const int c   = t & 63;
    const int oct = t >> 6;
    const int og  = blockIdx.x * 4 + oct;     // global octet (8 tokens)
    const int b   = og / (N_ / 8);
    const int po  = og % (N_ / 8);
    const int h0  = po / 7;
    const int w0  = (po - h0 * 7) * 8;

    float q8[8], k8[8], v8[8];
    const float bqc = bq[c], bkc = bk[c], bvc = bv[c];
    #pragma unroll
    for (int i = 0; i < 8; ++i) { q8[i] = bqc; k8[i] = bkc; v8[i] = bvc; }

    #pragma unroll
    for (int dh = 0; dh < 3; ++dh) {
        int hh = h0 + dh - 1;
        if (hh < 0 || hh >= H_) continue;
        float xv[10];
        #pragma unroll
        for (int j = 0; j < 10; ++j) {
            int ww = w0 + j - 1;
            xv[j] = (ww >= 0 && ww < W_) ? x[(((size_t)b * H_ + hh) * W_ + ww) * C_ + c] : 0.f;
        }
        #pragma unroll
        for (int dw = 0; dw < 3; ++dw) {
            float fq = wq[(dh * 3 + dw) * C_ + c];
            float fk = wk[(dh * 3 + dw) * C_ + c];
            float fv = wv[(dh * 3 + dw) * C_ + c];
            #pragma unroll
            for (int i = 0; i < 8; ++i) {
                float xs = xv[i + dw];
                q8[i] = fmaf(xs, fq, q8[i]);
                k8[i] = fmaf(xs, fk, k8[i]);
                v8[i] = fmaf(xs, fv, v8[i]);
            }
        }
    }
    #pragma unroll
    for (int i = 0; i < 8; ++i) q8[i] *= SCALE_LOG2;

    // ---- v: pack hi, fragment-major: [og>>2][g=og&3][c] ----
    {
        uint4 vh4; unsigned* vh = (unsigned*)&vh4;
        #pragma unroll
        for (int j = 0; j < 4; ++j) vh[j] = pack_bf2(v8[2*j], v8[2*j+1]);
        *(uint4*)&vf[((size_t)(og >> 2)) * 4096 + (og & 3) * 1024 + c * 16] = vh4;
    }

    // ---- q,k: LDS transpose to token-major, pack hi/lo, store frag-major ----
    #pragma unroll
    for (int i = 0; i < 8; ++i) { tq[oct * 8 + i][c] = q8[i]; tk[oct * 8 + i][c] = k8[i]; }
    __syncthreads();

    const int g2 = t & 7;       // channel group (8 ch = one 16B fragment)
    const int tl = t >> 3;      // token-local 0..31
    float qv[8], kv[8];
    *(float4*)&qv[0] = *(const float4*)&tq[tl][8 * g2];
    *(float4*)&qv[4] = *(const float4*)&tq[tl][8 * g2 + 4];
    *(float4*)&kv[0] = *(const float4*)&tk[tl][8 * g2];
    *(float4*)&kv[4] = *(const float4*)&tk[tl][8 * g2 + 4];

    uint4 qh4, ql4, kh4, kl4;
    unsigned* qh = (unsigned*)&qh4; unsigned* ql = (unsigned*)&ql4;
    unsigned* kh = (unsigned*)&kh4; unsigned* kl = (unsigned*)&kl4;
    #pragma unroll
    for (int j = 0; j < 4; ++j) {
        float a0 = qv[2*j], a1 = qv[2*j+1];
        qh[j] = pack_bf2(a0, a1);
        ql[j] = pack_bf2(a0 - bf16lo_f(qh[j] & 0xFFFFu), a1 - bf16hi_f(qh[j]));
        float k0 = kv[2*j], k1 = kv[2*j+1];
        kh[j] = pack_bf2(k0, k1);
        kl[j] = pack_bf2(k0 - bf16lo_f(kh[j] & 0xFFFFu), k1 - bf16hi_f(kh[j]));
    }
    const int nf = blockIdx.x * 32 + tl;      // flat token (b*N_+n)
    const size_t tb = ((size_t)(nf >> 5)) * 8192;   // (b*98 + tile32) * 8KB
    *(uint4*)&qf[tb +        g2 * 512 + tl * 16] = qh4;
    *(uint4*)&qf[tb + 4096 + g2 * 512 + tl * 16] = ql4;
    *(uint4*)&kf[tb +        g2 * 512 + tl * 16] = kh4;
    *(uint4*)&kf[tb + 4096 + g2 * 512 + tl * 16] = kl4;
}

// ---------------------------------------------------------------------------
// Kernel 2: MFMA flash attention — NO LDS, NO barriers, 1-wave blocks.
// grid = 3136: bx = ((ks*98 + qt32)<<3)|b  (b -> XCD L2 affinity).
// KSPLIT=4 (24-25 chunks/wave). Partials stored PACKED bf16: word =
// (bf16(ctx[c]) | bf16(ctx[c+32])<<16), layout [bx][cpair:32][q:32] u32.
// Numerics otherwise identical to R9 (hi/lo P, 3-term QK, shfl_xor).
// ---------------------------------------------------------------------------
__global__ __launch_bounds__(64, 4)
void attn_part(const uint8_t* __restrict__ qf, const uint8_t* __restrict__ kf,
               const uint8_t* __restrict__ vf,
               unsigned* __restrict__ part, float* __restrict__ ml) {
    const int lane = threadIdx.x;
    const int h    = lane >> 5;
    const int l31  = lane & 31;
    const int bx   = blockIdx.x;
    const int b    = bx & 7;
    const int r    = bx >> 3;        // 0..391
    const int ks   = r / NCH;
    const int qt   = r % NCH;

    const int c_beg = (NCH * ks) / KSPLIT;
    const int c_end = (NCH * (ks + 1)) / KSPLIT;

    // ---- Q fragments (B-operand), lane-linear ----
    const uint8_t* qb = qf + ((size_t)(b * NCH + qt)) * 8192;
    short8 qh[4], ql[4];
    #pragma unroll
    for (int s = 0; s < 4; ++s) {
        qh[s] = ldf(qb + s * 1024 + lane * 16);
        ql[s] = ldf(qb + 4096 + s * 1024 + lane * 16);
    }

    f32x16 ctx0, ctx1;
    #pragma unroll
    for (int i = 0; i < 16; ++i) { ctx0[i] = 0.f; ctx1[i] = 0.f; }
    float mrun = -INFINITY, lrun = 0.f;

    for (int ch = c_beg; ch < c_end; ++ch) {
        const uint8_t* kb = kf + ((size_t)(b * NCH + ch)) * 8192;
        const uint8_t* vb = vf + ((size_t)(b * NCH + ch)) * 4096;
        short8 kh0 = ldf(kb +        lane * 16);
        short8 kh1 = ldf(kb + 1024 + lane * 16);
        short8 kh2 = ldf(kb + 2048 + lane * 16);
        short8 kh3 = ldf(kb + 3072 + lane * 16);
        short8 kl0 = ldf(kb + 4096 + lane * 16);
        short8 kl1 = ldf(kb + 5120 + lane * 16);
        short8 kl2 = ldf(kb + 6144 + lane * 16);
        short8 kl3 = ldf(kb + 7168 + lane * 16);
        short8 v00 = ldf(vb +        h * 1024 + l31 * 16);        // S=0, c 0-31
        short8 v10 = ldf(vb +  512 + h * 1024 + l31 * 16);        // S=0, c 32-63
        short8 v01 = ldf(vb + 2048 + h * 1024 + l31 * 16);        // S=1, c 0-31
        short8 v11 = ldf(vb + 2560 + h * 1024 + l31 * 16);        // S=1, c 32-63

        // ---- S^T = K * Q^T (hi/lo 3-term), 32k x 32q ----
        f32x16 s0;
        #pragma unroll
        for (int i = 0; i < 16; ++i) s0[i] = 0.f;
        s0 = MF(kh0, qh[0], s0); s0 = MF(kh0, ql[0], s0); s0 = MF(kl0, qh[0], s0);
        s0 = MF(kh1, qh[1], s0); s0 = MF(kh1, ql[1], s0); s0 = MF(kl1, qh[1], s0);
        s0 = MF(kh2, qh[2], s0); s0 = MF(kh2, ql[2], s0); s0 = MF(kl2, qh[2], s0);
        s0 = MF(kh3, qh[3], s0); s0 = MF(kh3, ql[3], s0); s0 = MF(kl3, qh[3], s0);

        // ---- online softmax (log2 domain) ----
        float t0 = fmaxf(fmaxf(s0[0],  s0[1]),  s0[2]);
        float t1 = fmaxf(fmaxf(s0[3],  s0[4]),  s0[5]);
        float t2 = fmaxf(fmaxf(s0[6],  s0[7]),  s0[8]);
        float t3 = fmaxf(fmaxf(s0[9],  s0[10]), s0[11]);
        float t4 = fmaxf(fmaxf(s0[12], s0[13]), s0[14]);
        float mloc = fmaxf(fmaxf(fmaxf(t0, t1), s0[15]), fmaxf(fmaxf(t2, t3), t4));
        float mw = fmaxf(mloc, __shfl_xor(mloc, 32));
        if (mw > mrun + 8.f) {          // defer-max (T13)
            float fac = exp2_fast(mrun - mw);
            lrun *= fac;
            #pragma unroll
            for (int i = 0; i < 16; ++i) { ctx0[i] *= fac; ctx1[i] *= fac; }
            mrun = mw;
        }
        float p0[16];
        float lsum = 0.f;
        #pragma unroll
        for (int i = 0; i < 16; ++i) { p0[i] = exp2_fast(s0[i] - mrun); lsum += p0[i]; }
        lrun += lsum + __shfl_xor(lsum, 32);

        // ---- P -> bf16 hi/lo words ----
        unsigned hw0[8], lw0[8];
        #pragma unroll
        for (int j = 0; j < 8; ++j) {
            hw0[j] = pack_bf2(p0[2*j], p0[2*j+1]);
            lw0[j] = pack_bf2(p0[2*j]   - bf16lo_f(hw0[j] & 0xFFFFu),
                              p0[2*j+1] - bf16hi_f(hw0[j]));
        }

        // ---- PV: partner word exchange -> B-frags; A = V from regs ----
#define PV_STEP(S, VA, VB) {                                                  \
        const int base = 4 * (S);                                             \
        unsigned a0 = hw0[base], a1 = hw0[base+1], a2 = hw0[base+2], a3 = hw0[base+3]; \
        unsigned c0 = lw0[base], c1 = lw0[base+1], c2 = lw0[base+2], c3 = lw0[base+3]; \
        unsigned sh0 = __shfl_xor(h ? a0 : a2, 32);                           \
        unsigned sh1 = __shfl_xor(h ? a1 : a3, 32);                           \
        unsigned sl0 = __shfl_xor(h ? c0 : c2, 32);                           \
        unsigned sl1 = __shfl_xor(h ? c1 : c3, 32);                           \
        short8 bh = frag_words(h ? sh0 : a0, h ? sh1 : a1,                    \
                               h ? a2 : sh0, h ? a3 : sh1);                   \
        short8 bl = frag_words(h ? sl0 : c0, h ? sl1 : c1,                    \
                               h ? c2 : sl0, h ? c3 : sl1);                   \
        ctx0 = MF(VA, bh, ctx0);  ctx1 = MF(VB, bh, ctx1);                    \
        ctx0 = MF(VA, bl, ctx0);  ctx1 = MF(VB, bl, ctx1);                    \
    }
        PV_STEP(0, v00, v10)
        PV_STEP(1, v01, v11)
#undef PV_STEP
    }

    // ---- write partials packed bf16: part[bx][cpair:32][q:32] u32 ----
    unsigned* pbase = part + (size_t)bx * 1024;
    #pragma unroll
    for (int u = 0; u < 4; ++u)
        #pragma unroll
        for (int rr = 0; rr < 4; ++rr) {
            const int i  = 4 * u + rr;
            const int cc = 8 * u + 4 * h + rr;    // 0..31 (cpair)
            pbase[cc * 32 + l31] = pack_bf2(ctx0[i], ctx1[i]);
        }
    if (h == 0)
        ((float2*)ml)[(size_t)bx * 32 + l31] = make_float2(mrun, lrun);
}

// ---------------------------------------------------------------------------
// Kernel 3: combine 4 K-split packed-bf16 partials + projection. grid = 392:
// bx = (g<<3)|b, g = 0..48, each block does 64 q-rows (two 32-row tiles).
// ---------------------------------------------------------------------------
__global__ __launch_bounds__(256)
void combine(const unsigned* __restrict__ part, const float* __restrict__ ml,
             const float* __restrict__ Wp, const float* __restrict__ bp,
             float* __restrict__ out) {
    __shared__ float cm[64][68];        // merged+normalized ctx, c-major
    __shared__ float fac[KSPLIT][64];

    const int bx = blockIdx.x;
    const int b  = bx & 7;
    const int g  = bx >> 3;             // 0..48
    const int t  = threadIdx.x;

    if (t < 64) {
        const int qt   = g * 2 + (t >> 5);
        const int qrow = t & 31;
        float m8[KSPLIT], l8[KSPLIT];
        #pragma unroll
        for (int ks = 0; ks < KSPLIT; ++ks) {
            float2 v = ((const float2*)ml)[((size_t)(((ks * NCH + qt) << 3) | b)) * 32 + qrow];
            m8[ks] = v.x; l8[ks] = v.y;
        }
        float M = m8[0];
        #pragma unroll
        for (int ks = 1; ks < KSPLIT; ++ks) M = fmaxf(M, m8[ks]);
        float L = 0.f;
        float f[KSPLIT];
        #pragma unroll
        for (int ks = 0; ks < KSPLIT; ++ks) { f[ks] = exp2f(m8[ks] - M); L = fmaf(l8[ks], f[ks], L); }
        float inv = 1.f / L;
        #pragma unroll
        for (int ks = 0; ks < KSPLIT; ++ks) fac[ks][t] = f[ks] * inv;
    }
    __syncthreads();

    // ---- merge: rep = tile (0,1); thread t -> (cp = t>>3, q4 = t&7).
    // uint4 read = 4 words = 4 consecutive q of one cpair -> fully linear 4KB.
    #pragma unroll
    for (int rep = 0; rep < 2; ++rep) {
        const int cp = t >> 3;            // 0..31
        const int q4 = t & 7;             // 0..7 -> q = q4*4..+3
        float accL[4] = {0.f, 0.f, 0.f, 0.f};
        float accH[4] = {0.f, 0.f, 0.f, 0.f};
        #pragma unroll
        for (int ks = 0; ks < KSPLIT; ++ks) {
            const uint4 w4 = *(const uint4*)&part[((size_t)(((ks * NCH + g * 2 + rep) << 3) | b)) * 1024
                                                  + cp * 32 + q4 * 4];
            const unsigned* w = (const unsigned*)&w4;
            #pragma unroll
            for (int j = 0; j < 4; ++j) {
                const float fj = fac[ks][rep * 32 + q4 * 4 + j];
                accL[j] = fmaf(bf16lo_f(w[j]), fj, accL[j]);
                accH[j] = fmaf(bf16hi_f(w[j]), fj, accH[j]);
            }
        }
        #pragma unroll
        for (int j = 0; j < 4; ++j) {
            cm[cp][rep * 32 + q4 * 4 + j]      = accL[j];
            cm[cp + 32][rep * 32 + q4 * 4 + j] = accH[j];
        }
    }
    __syncthreads();

    // ---- projection: thread -> (q = t>>2, eq = t&3): 16 e-cols each ----
    {
        const int q = t >> 2, eq = t & 3;
        float4 y[4];
        #pragma unroll
        for (int e = 0; e < 4; ++e) y[e] = *(const float4*)&bp[eq * 16 + e * 4];
        for (int cc = 0; cc < 64; ++cc) {
            float v = cm[cc][q];
            const float4* w4 = (const float4*)&Wp[cc * 64 + eq * 16];
            #pragma unroll
            for (int e = 0; e < 4; ++e) {
                float4 wv4 = w4[e];
                y[e].x = fmaf(v, wv4.x, y[e].x);
                y[e].y = fmaf(v, wv4.y, y[e].y);
                y[e].z = fmaf(v, wv4.z, y[e].z);
                y[e].w = fmaf(v, wv4.w, y[e].w);
            }
        }
        const int n = g * 64 + q;             // < 3136 always (49*64 = 3136)
        float4* op = (float4*)&out[((size_t)b * N_ + n) * 64 + eq * 16];
        #pragma unroll
        for (int e = 0; e < 4; ++e) op[e] = y[e];
    }
}

// ---------------------------------------------------------------------------
extern "C" void kernel_launch(void* const* d_in, const int* in_sizes, int n_in,
                              void* d_out, int out_size, void* d_ws, size_t ws_size,
                              hipStream_t stream) {
    const float* x  = (const float*)d_in[0];
    const float* wq = (const float*)d_in[1];
    const float* bq = (const float*)d_in[2];
    const float* wk = (const float*)d_in[3];
    const float* bk = (const float*)d_in[4];
    const float* wv = (const float*)d_in[5];
    const float* bv = (const float*)d_in[6];
    const float* Wp = (const float*)d_in[7];
    const float* bp = (const float*)d_in[8];
    float* out = (float*)d_out;

    const size_t qk_bytes = (size_t)B_ * NCH * 8192;   // 6,422,528 each
    const size_t vf_bytes = (size_t)B_ * NCH * 4096;   // 3,211,264
    uint8_t*  qf = (uint8_t*)d_ws;
    uint8_t*  kf = qf + qk_bytes;
    uint8_t*  vf = kf + qk_bytes;
    unsigned* partp = (unsigned*)(vf + vf_bytes);      // [3136][32][32] u32 (bf16x2)
    float*    mlp   = (float*)(partp + (size_t)3136 * 1024);   // [3136][32][2] f32

    dwconv_fused<<<784, 256, 0, stream>>>(x, wq, bq, wk, bk, wv, bv, qf, kf, vf);
    attn_part<<<KSPLIT * NCH * 8, 64, 0, stream>>>(qf, kf, vf, partp, mlp);
    combine<<<49 * 8, 256, 0, stream>>>(partp, mlp, Wp, bp, out);
}